// Round 5
// baseline (366.850 us; speedup 1.0000x reference)
//
#include <hip/hip_runtime.h>
#include <hip/hip_bf16.h>
#include <math.h>

#define NN 65536
#define MM 32
#define KK 32

#define HALF_LOG_2PI 0.91893853320467274178f
#define L2E 1.44269504088896340736f
#define TTG_EPS 2.2204460492503131e-16f

typedef __attribute__((ext_vector_type(4))) float f32x4;
typedef __attribute__((ext_vector_type(2))) float f32x2;

static __device__ __forceinline__ float fast_exp2(float x) {
#if __has_builtin(__builtin_amdgcn_exp2f)
  return __builtin_amdgcn_exp2f(x);
#else
  float r;
  // single hardware exp2; s_nop covers the trans->consumer hazard window
  asm("v_exp_f32 %0, %1\n\ts_nop 1" : "=v"(r) : "v"(x));
  return r;
#endif
}

// ws layout (floats):
//   [0..31]   softmax(wk0)
//   [64 ...]  params as float4, plane layout:
//             float4 index = ((i*3 + p)*8 + jq)*32 + k,  component = j&3  (j = jq*4 + jc)
//             p: 0=P0, 1=P1, 2=P2.  exp2-argument = P0 + P1*x + P2*x^2.
__global__ void ttg_precompute(const float* __restrict__ wk0_logits,
                               const float* __restrict__ W_logits,
                               const float* __restrict__ mu,
                               const float* __restrict__ pre_sigma,
                               float* __restrict__ ws) {
  int i = blockIdx.x;  // 0..31
  __shared__ float wsl[1024];
  __shared__ float lse[32];
  for (int t = threadIdx.x; t < 1024; t += blockDim.x)
    wsl[t] = W_logits[i * 1024 + t];
  __syncthreads();
  if (threadIdx.x < 32) {
    int j = threadIdx.x;
    float mx = -1e30f;
    for (int k = 0; k < 32; ++k) mx = fmaxf(mx, wsl[k * 32 + j]);
    float s = 0.f;
    for (int k = 0; k < 32; ++k) s += expf(wsl[k * 32 + j] - mx);
    lse[j] = mx + logf(s);
  }
  __syncthreads();
  float* params = ws + 64;
  for (int t = threadIdx.x; t < 1024; t += blockDim.x) {
    int k = t >> 5, j = t & 31;
    float ps = pre_sigma[t];
    float sg = log1pf(expf(-fabsf(ps))) + fmaxf(ps, 0.f);  // softplus
    float a = 1.f / sg;
    float b = mu[t] * a;
    float lw = wsl[t] - lse[j];
    float c = lw - logf(sg) - HALF_LOG_2PI;
    float P0 = (c - 0.5f * b * b) * L2E;
    float P1 = (a * b) * L2E;
    float P2 = (-0.5f * a * a) * L2E;
    int jq = j >> 2, jc = j & 3;
    params[((((i * 3 + 0) * 8 + jq) * 32) + k) * 4 + jc] = P0;
    params[((((i * 3 + 1) * 8 + jq) * 32) + k) * 4 + jc] = P1;
    params[((((i * 3 + 2) * 8 + jq) * 32) + k) * 4 + jc] = P2;
  }
  if (i == 0 && threadIdx.x < 32) {
    float mx = -1e30f;
    for (int j = 0; j < 32; ++j) mx = fmaxf(mx, wk0_logits[j]);
    float s = 0.f;
    for (int j = 0; j < 32; ++j) s += expf(wk0_logits[j] - mx);
    ws[threadIdx.x] = expf(wk0_logits[threadIdx.x] - mx) / s;
  }
}

// 256 threads = 4 independent waves, no __syncthreads in the main loop.
// Lane L: k = L&31 (output row), sh = L>>5. Wave owns 16 samples; per pair-slot
// tt the two half-waves process samples 2tt and 2tt+1.
// Params are loaded 48-floats-at-a-time and PINNED in VGPRs via an empty asm
// with "+v" constraints — rounds 2-4 showed the compiler otherwise fissions
// the loop and re-reads params per quad (VGPR_Count=52, ~8 extra cyc/elem).
__global__ __launch_bounds__(256, 4) void ttg_main(const float* __restrict__ X,
                                                   const float* __restrict__ ws,
                                                   float* __restrict__ out) {
  __shared__ __align__(16) float vbuf[4][16][32];    // [wave][sample][k]  8 KB
  __shared__ __align__(8)  f32x2 xbuf[4][16][32];    // [wave][sample][i] = (x, x^2)  16 KB
  const int t = threadIdx.x;
  const int wv = t >> 6;
  const int L = t & 63;
  const int k = L & 31;
  const int sh = L >> 5;
  const int n0 = (blockIdx.x * 4 + wv) * 16;

  // stage x (+x^2), fully coalesced
  for (int r = 0; r < 8; ++r) {
    int f = L + 64 * r;  // 0..511
    int s = f >> 5, i = f & 31;
    float x = X[n0 * 32 + f];
    xbuf[wv][s][i] = (f32x2){x, x * x};
  }
  // init v = softmax(wk0)
  {
    float w0 = ws[k];
#pragma unroll
    for (int rep = 0; rep < 8; ++rep)
      vbuf[wv][rep * 2 + sh][k] = w0;
  }

  const f32x4* __restrict__ P = (const f32x4*)(ws + 64);

  for (int i = 0; i < 32; ++i) {
    const f32x4* Pi = P + i * 768 + k;
    f32x4 q0[4], q1[4], q2[4];
    float acc[8];

    // ---- half A: j-quads 0..3 ----
#pragma unroll
    for (int jq = 0; jq < 4; ++jq) {
      q0[jq] = Pi[jq * 32];
      q1[jq] = Pi[256 + jq * 32];
      q2[jq] = Pi[512 + jq * 32];
    }
    asm volatile("" : "+v"(q0[0]), "+v"(q0[1]), "+v"(q0[2]), "+v"(q0[3]),
                      "+v"(q1[0]), "+v"(q1[1]), "+v"(q1[2]), "+v"(q1[3]),
                      "+v"(q2[0]), "+v"(q2[1]), "+v"(q2[2]), "+v"(q2[3]));
#pragma unroll
    for (int tt = 0; tt < 8; ++tt) {
      const int s = tt * 2 + sh;
      f32x2 xx = xbuf[wv][s][i];
      float a = 0.f;
#pragma unroll
      for (int jq = 0; jq < 4; ++jq) {
        f32x4 v4 = *(const f32x4*)&vbuf[wv][s][jq * 4];  // broadcast b128
        a = fmaf(v4.x, fast_exp2(fmaf(q2[jq].x, xx.y, fmaf(q1[jq].x, xx.x, q0[jq].x))), a);
        a = fmaf(v4.y, fast_exp2(fmaf(q2[jq].y, xx.y, fmaf(q1[jq].y, xx.x, q0[jq].y))), a);
        a = fmaf(v4.z, fast_exp2(fmaf(q2[jq].z, xx.y, fmaf(q1[jq].z, xx.x, q0[jq].z))), a);
        a = fmaf(v4.w, fast_exp2(fmaf(q2[jq].w, xx.y, fmaf(q1[jq].w, xx.x, q0[jq].w))), a);
      }
      acc[tt] = a;
    }

    // ---- half B: j-quads 4..7 ----
#pragma unroll
    for (int jq = 0; jq < 4; ++jq) {
      q0[jq] = Pi[(jq + 4) * 32];
      q1[jq] = Pi[256 + (jq + 4) * 32];
      q2[jq] = Pi[512 + (jq + 4) * 32];
    }
    asm volatile("" : "+v"(q0[0]), "+v"(q0[1]), "+v"(q0[2]), "+v"(q0[3]),
                      "+v"(q1[0]), "+v"(q1[1]), "+v"(q1[2]), "+v"(q1[3]),
                      "+v"(q2[0]), "+v"(q2[1]), "+v"(q2[2]), "+v"(q2[3]));
#pragma unroll
    for (int tt = 0; tt < 8; ++tt) {
      const int s = tt * 2 + sh;
      f32x2 xx = xbuf[wv][s][i];
      float a = acc[tt];
#pragma unroll
      for (int jq = 0; jq < 4; ++jq) {
        f32x4 v4 = *(const f32x4*)&vbuf[wv][s][(jq + 4) * 4];
        a = fmaf(v4.x, fast_exp2(fmaf(q2[jq].x, xx.y, fmaf(q1[jq].x, xx.x, q0[jq].x))), a);
        a = fmaf(v4.y, fast_exp2(fmaf(q2[jq].y, xx.y, fmaf(q1[jq].y, xx.x, q0[jq].y))), a);
        a = fmaf(v4.z, fast_exp2(fmaf(q2[jq].z, xx.y, fmaf(q1[jq].z, xx.x, q0[jq].z))), a);
        a = fmaf(v4.w, fast_exp2(fmaf(q2[jq].w, xx.y, fmaf(q1[jq].w, xx.x, q0[jq].w))), a);
      }
      acc[tt] = a;
    }

    if (i < 31) {
      // publish new v; all reads of step i precede these writes in wave
      // program order, and step i+1's reads follow them (in-order DS pipe).
#pragma unroll
      for (int tt = 0; tt < 8; ++tt)
        vbuf[wv][tt * 2 + sh][k] = acc[tt];
    } else {
      // final step: reduce over k within each half-wave and emit
#pragma unroll
      for (int tt = 0; tt < 8; ++tt) {
        float val = acc[tt];
        val += __shfl_xor(val, 1);
        val += __shfl_xor(val, 2);
        val += __shfl_xor(val, 4);
        val += __shfl_xor(val, 8);
        val += __shfl_xor(val, 16);
        if (k == 0) out[n0 + tt * 2 + sh] = logf(val + TTG_EPS);
      }
    }
  }
}

extern "C" void kernel_launch(void* const* d_in, const int* in_sizes, int n_in,
                              void* d_out, int out_size, void* d_ws, size_t ws_size,
                              hipStream_t stream) {
  const float* X          = (const float*)d_in[0];
  const float* wk0_logits = (const float*)d_in[1];
  const float* W_logits   = (const float*)d_in[2];
  const float* mu         = (const float*)d_in[3];
  const float* pre_sigma  = (const float*)d_in[4];
  float* out = (float*)d_out;
  float* ws  = (float*)d_ws;

  ttg_precompute<<<32, 256, 0, stream>>>(wk0_logits, W_logits, mu, pre_sigma, ws);
  ttg_main<<<1024, 256, 0, stream>>>(X, ws, out);
}